// Round 14
// baseline (87.813 us; speedup 1.0000x reference)
//
#include <hip/hip_runtime.h>
#include <hip/hip_bf16.h>

// Ball query: for each (b, p) center, collect first S point indices n with
// ||xyz[b,n] - center[b,p]||^2 < r^2 (index order), zero-fill the rest.
//
// FROZEN FP arithmetic (R6, bit-matches harness "np" ref = XLA w/ contraction):
//   cn = fma(cz,cz, fma(cy,cy, cx*cx))          (contracted mul+reduce)
//   xn = fma(z,z,   fma(y,y,   x*x))            (precomputed in pack kernel)
//   dot= fma(cz,z,  fma(cy,y,  cx*x))           (ascending-K FMA)
//   d2 = (cn + xn) - 2*dot ;  valid = d2 < r*r  (all fp32, strict <)
//   NOTE: d2 here uses fma(-2, dot, add(cn,xn)) — bit-identical to the frozen
//   sub(add, mul2) form because 2*dot is exact (single rounding either way).
// DO NOT reorder/refactor these ops — a rounding change flips boundary masks.
//
// R14: C=8 centers per block, sharing every staged point.
// R11-R13 post-mortems: instr count, L1 pattern, and latency structure all
// changed with ZERO effect -> bottleneck is L2 traffic (740 MB = 16384
// centers x ~2800 pts x 16 B through L2 at ~34.5 TB/s ~= 21 us ~= the
// observed kernel). Sharing each 1024-pt tile across 8 centers divides
// bytes/pair-eval by 8 (block scans to the max of its 8 centers; per-center
// done-skip keeps pair-evals ~= R11). Grid = 2048 blocks = exactly resident.
// NO global atomics (R9: 7x regression).

typedef float f32x4 __attribute__((ext_vector_type(4)));

#define C 8   // centers per block

__global__ __launch_bounds__(256) void pack_points(
    const float* __restrict__ xyz,   // [B*N, 3]
    f32x4* __restrict__ q,           // [B*N] packed {x,y,z,xn}
    int total)
{
    const int n = blockIdx.x * blockDim.x + threadIdx.x;
    if (n >= total) return;
    const float x = xyz[(size_t)n * 3 + 0];
    const float y = xyz[(size_t)n * 3 + 1];
    const float z = xyz[(size_t)n * 3 + 2];
    // FROZEN xn sequence:
    const float xn = __builtin_fmaf(z, z,
                      __builtin_fmaf(y, y, __fmul_rn(x, x)));
    f32x4 v;
    v[0] = x; v[1] = y; v[2] = z; v[3] = xn;
    q[n] = v;
}

__global__ __launch_bounds__(256) void ball_query_multi(
    const f32x4* __restrict__ q,          // [B*N] packed {x,y,z,xn}
    const float* __restrict__ center,     // [B, P, 3]
    const float* __restrict__ p_radius,   // [1]
    const int*   __restrict__ p_sample,   // [1]
    int* __restrict__ out,                // [B, P, S]
    int B, int N, int P)
{
    const int S = p_sample[0];
    const float r = p_radius[0];
    const float r2 = __fmul_rn(r, r);

    const int cbase = blockIdx.x * C;     // 8 consecutive centers (same batch:
    const int lane = threadIdx.x & 63;    //  P % C == 0, cbase % C == 0)
    const int wv = threadIdx.x >> 6;      // wave 0..3

    const int b = cbase / P;

    // Load the 8 centers (uniform addresses -> scalar loads)
    float cxk[C], cyk[C], czk[C], cnk[C];
#pragma unroll
    for (int k = 0; k < C; ++k) {
        const float cx = center[(size_t)(cbase + k) * 3 + 0];
        const float cy = center[(size_t)(cbase + k) * 3 + 1];
        const float cz = center[(size_t)(cbase + k) * 3 + 2];
        cxk[k] = cx; cyk[k] = cy; czk[k] = cz;
        // FROZEN cn sequence:
        cnk[k] = __builtin_fmaf(cz, cz,
                  __builtin_fmaf(cy, cy, __fmul_rn(cx, cx)));
    }

    const f32x4* qb = q + (size_t)b * N;

    __shared__ int counts[2][4][C];       // [buf][wave][center]

    int cnt[C];
#pragma unroll
    for (int k = 0; k < C; ++k) cnt[k] = 0;

    int buf = 0;
    for (int n0 = 0; n0 < N; n0 += 1024) {
        const int base = n0 + wv * 256 + lane;   // wave wv -> chunks 4wv..4wv+3

        // Stage 4 chunks (1024 pts/block) — paid ONCE for all 8 centers.
        f32x4 v[4];
#pragma unroll
        for (int j = 0; j < 4; ++j) {
            v[j] = qb[base + j * 64];
        }

        // Per-center masks + wave totals (skip finished centers).
        unsigned vb[C];
        int wtot[C];
#pragma unroll
        for (int k = 0; k < C; ++k) {
            vb[k] = 0; wtot[k] = 0;
            if (cnt[k] >= S) continue;            // uniform skip
            unsigned bits = 0;
            int t = 0;
#pragma unroll
            for (int j = 0; j < 4; ++j) {
                const float x = v[j][0], y = v[j][1], z = v[j][2];
                const float xn = v[j][3];         // FROZEN xn (precomputed)
                // FROZEN per-pair FP sequence:
                const float dot = __builtin_fmaf(czk[k], z,
                                   __builtin_fmaf(cyk[k], y,
                                                  __fmul_rn(cxk[k], x)));
                const float s = __fadd_rn(cnk[k], xn);
                const float d2 = __builtin_fmaf(-2.0f, dot, s);
                const unsigned long long m = __ballot(d2 < r2);
                bits |= ((unsigned)((m >> lane) & 1ull)) << j;
                t += __popcll(m);
            }
            vb[k] = bits; wtot[k] = t;
        }
        if (lane == 0) {
#pragma unroll
            for (int k = 0; k < C; ++k) counts[buf][wv][k] = wtot[k];
        }
        __syncthreads();

        // Ordered writes + count update per active center.
        bool alldone = true;
#pragma unroll
        for (int k = 0; k < C; ++k) {
            if (cnt[k] >= S) continue;
            const int c0 = counts[buf][0][k];
            const int c1 = counts[buf][1][k];
            const int c2 = counts[buf][2][k];
            const int c3 = counts[buf][3][k];
            const int total = (c0 + c1) + (c2 + c3);
            if (wtot[k] != 0) {                   // wave-uniform skip
                int prefix = 0;
                if (wv > 0) prefix += c0;
                if (wv > 1) prefix += c1;
                if (wv > 2) prefix += c2;
                int off = cnt[k] + prefix;
                int* ob = out + (size_t)(cbase + k) * S;
#pragma unroll
                for (int j = 0; j < 4; ++j) {
                    const unsigned long long m = __ballot((vb[k] >> j) & 1u);
                    const bool valid = (m >> lane) & 1ull;
                    const int rank = __builtin_amdgcn_mbcnt_hi(
                        (unsigned)(m >> 32),
                        __builtin_amdgcn_mbcnt_lo((unsigned)m, 0u));
                    const int slot = off + rank;
                    if (valid && slot < S) {
                        ob[slot] = base + j * 64;
                    }
                    off += __popcll(m);
                }
            }
            cnt[k] += total;
            if (cnt[k] < S) alldone = false;
        }
        buf ^= 1;
        if (alldone) break;                       // uniform across block
    }

    // Zero-fill unused slots for all 8 centers (harness poisons d_out).
#pragma unroll
    for (int k = 0; k < C; ++k) {
        int e = cnt[k] > S ? S : cnt[k];
        int* ob = out + (size_t)(cbase + k) * S;
        for (int s = e + (int)threadIdx.x; s < S; s += 256) {
            ob[s] = 0;
        }
    }
}

extern "C" void kernel_launch(void* const* d_in, const int* in_sizes, int n_in,
                              void* d_out, int out_size, void* d_ws, size_t ws_size,
                              hipStream_t stream) {
    const float* xyz      = (const float*)d_in[0];   // [B, N, 3]
    const float* center   = (const float*)d_in[1];   // [B, P, 3]
    const float* p_radius = (const float*)d_in[2];   // scalar
    const int*   p_sample = (const int*)d_in[3];     // scalar

    const int B = 8;
    const int N = in_sizes[0] / (B * 3);   // 16384
    const int P = in_sizes[1] / (B * 3);   // 2048

    int* out = (int*)d_out;
    f32x4* q = (f32x4*)d_ws;               // B*N*16 B = 2 MB << ws_size

    // Pass 1: pack {x,y,z,xn}
    const int total = B * N;               // 131072
    pack_points<<<(total + 255) / 256, 256, 0, stream>>>(xyz, q, total);

    // Pass 2: 8 centers per block -> 2048 blocks (exactly resident at 8/CU).
    const int blocks = (B * P) / C;        // 2048
    const int threads = 256;
    ball_query_multi<<<blocks, threads, 0, stream>>>(
        q, center, p_radius, p_sample, out, B, N, P);
}

// Round 15
// 81.149 us; speedup vs baseline: 1.0821x; 1.0821x over previous
//
#include <hip/hip_runtime.h>
#include <hip/hip_bf16.h>

// Ball query: for each (b, p) center, collect first S point indices n with
// ||xyz[b,n] - center[b,p]||^2 < r^2 (index order), zero-fill the rest.
//
// FROZEN FP arithmetic (R6, bit-matches harness "np" ref = XLA w/ contraction):
//   cn = fma(cz,cz, fma(cy,cy, cx*cx))          (contracted mul+reduce)
//   xn = fma(z,z,   fma(y,y,   x*x))            (precomputed in pack kernel;
//                                                fp32 store/reload bit-exact)
//   dot= fma(cz,z,  fma(cy,y,  cx*x))           (ascending-K FMA)
//   d2 = (cn + xn) - 2*dot ;  valid = d2 < r*r  (all fp32, strict <)
// DO NOT reorder/refactor these ops — a rounding change flips boundary masks.
//
// R15: minimal-coupling structure. Killed theories: straggler latency
// (R8/R11), occupancy (R9), L1 transactions (R12), instr count (R13),
// L2 bytes (R14) — all land at kernel ~37-44us. Common residue: per-wave
// serial iteration chain (loads gated by previous ballot via cnt<S) and
// 256-thread blocks (block-granular wave retirement). This round:
//   - ONE wave per center in its OWN 64-thread block: no barriers, no
//     sibling waves pinned by a long scan, independent retirement.
//   - packed q[n]={x,y,z,xn} aligned 16-B loads (R13, proven bit-exact).
//   - 8 chunks (512 points) of loads in flight per iteration (2x R7 MLP).
// NO global atomics (R9: 7x regression).

typedef float f32x4 __attribute__((ext_vector_type(4)));

__global__ __launch_bounds__(256) void pack_points(
    const float* __restrict__ xyz,   // [B*N, 3]
    f32x4* __restrict__ q,           // [B*N] packed {x,y,z,xn}
    int total)
{
    const int n = blockIdx.x * blockDim.x + threadIdx.x;
    if (n >= total) return;
    const float x = xyz[(size_t)n * 3 + 0];
    const float y = xyz[(size_t)n * 3 + 1];
    const float z = xyz[(size_t)n * 3 + 2];
    // FROZEN xn sequence:
    const float xn = __builtin_fmaf(z, z,
                      __builtin_fmaf(y, y, __fmul_rn(x, x)));
    f32x4 v;
    v[0] = x; v[1] = y; v[2] = z; v[3] = xn;
    q[n] = v;
}

__global__ __launch_bounds__(64) void ball_query_wave(
    const f32x4* __restrict__ q,          // [B*N] packed {x,y,z,xn}
    const float* __restrict__ center,     // [B, P, 3]
    const float* __restrict__ p_radius,   // [1]
    const int*   __restrict__ p_sample,   // [1]
    int* __restrict__ out,                // [B, P, S]
    int B, int N, int P)
{
    const int S = p_sample[0];
    const float r = p_radius[0];
    const float r2 = __fmul_rn(r, r);

    const int c = blockIdx.x;             // one 64-thread block = one wave = one center
    const int lane = threadIdx.x;         // 0..63

    const int b = c / P;

    // Center coords + squared norm (uniform address -> broadcast)
    const float cx = center[(size_t)c * 3 + 0];
    const float cy = center[(size_t)c * 3 + 1];
    const float cz = center[(size_t)c * 3 + 2];
    // FROZEN cn sequence:
    const float cn = __builtin_fmaf(cz, cz,
                      __builtin_fmaf(cy, cy, __fmul_rn(cx, cx)));

    const f32x4* qb = q + (size_t)b * N;
    int* ob = out + (size_t)c * S;

    int cnt = 0;
    // N = 16384 = 32 batches of 512; early exit at 512 granularity.
    for (int n0 = 0; n0 < N && cnt < S; n0 += 512) {
        // Phase 1: 8 independent aligned dwordx4 loads — all in flight.
        f32x4 v[8];
#pragma unroll
        for (int j = 0; j < 8; ++j) {
            v[j] = qb[n0 + j * 64 + lane];
        }

        // Phase 2: 8 ballot phases in ascending chunk order.
#pragma unroll
        for (int j = 0; j < 8; ++j) {
            const float x = v[j][0], y = v[j][1], z = v[j][2];
            const float xn = v[j][3];     // FROZEN xn (precomputed, bit-exact)
            // FROZEN per-pair FP sequence:
            const float dot = __builtin_fmaf(cz, z,
                               __builtin_fmaf(cy, y, __fmul_rn(cx, x)));
            const float d2 = __fsub_rn(__fadd_rn(cn, xn), __fmul_rn(2.0f, dot));

            const bool valid = d2 < r2;
            const unsigned long long m = __ballot(valid);
            const int rank = __builtin_amdgcn_mbcnt_hi(
                (unsigned)(m >> 32),
                __builtin_amdgcn_mbcnt_lo((unsigned)m, 0u));
            if (valid && (cnt + rank) < S) {
                ob[cnt + rank] = n0 + j * 64 + lane;
            }
            cnt += __popcll(m);
        }
    }

    // Zero-fill unused slots (harness poisons d_out).
    if (cnt > S) cnt = S;
    for (int s = cnt + lane; s < S; s += 64) {
        ob[s] = 0;
    }
}

extern "C" void kernel_launch(void* const* d_in, const int* in_sizes, int n_in,
                              void* d_out, int out_size, void* d_ws, size_t ws_size,
                              hipStream_t stream) {
    const float* xyz      = (const float*)d_in[0];   // [B, N, 3]
    const float* center   = (const float*)d_in[1];   // [B, P, 3]
    const float* p_radius = (const float*)d_in[2];   // scalar
    const int*   p_sample = (const int*)d_in[3];     // scalar

    const int B = 8;
    const int N = in_sizes[0] / (B * 3);   // 16384
    const int P = in_sizes[1] / (B * 3);   // 2048

    int* out = (int*)d_out;
    f32x4* q = (f32x4*)d_ws;               // B*N*16 B = 2 MB << ws_size

    // Pass 1: pack {x,y,z,xn}
    const int total = B * N;               // 131072
    pack_points<<<(total + 255) / 256, 256, 0, stream>>>(xyz, q, total);

    // Pass 2: one wave (own 64-thread block) per center.
    const int blocks = B * P;              // 16384
    ball_query_wave<<<blocks, 64, 0, stream>>>(
        q, center, p_radius, p_sample, out, B, N, P);
}